// Round 16
// baseline (5437.429 us; speedup 1.0000x reference)
//
#include <hip/hip_runtime.h>
#include <math.h>

#define NSTEPS 200
#define NT     256          // 4 waves; wave w owns cols [w*32, w*32+32) (2 nt)
#define BR     32           // rows per block; grid 1024 = exactly 4 resident/CU
#define SQDT_F 0.07071067811865475f
#define DT_F   0.005f
#define LOSCL  4096.0f            // 2^12
#define LOINV  2.44140625e-4f     // 2^-12

typedef float  f32x4 __attribute__((ext_vector_type(4)));
typedef short  s16x8 __attribute__((ext_vector_type(8)));
typedef _Float16 h16x8 __attribute__((ext_vector_type(8)));
typedef unsigned short u16;
typedef unsigned short us4 __attribute__((ext_vector_type(4)));

// prepacked weight offsets in u16 units (each 128x128 matrix = 32768 u16 as hi/lo frags)
#define ENC_OFF 0
#define W1_OFF  32768
#define W2_OFF  65536
#define WG0_OFF 98304
#define WG1_OFF 131072
#define DEC_OFF 163840
#define WPK_TOT 196608

// ---- fp16 scaled two-term split: x ~= hi + lo*2^-12, |err| <= ~2^-23 |x| ----
__device__ __forceinline__ u16 f2h(float v) {
    _Float16 h = (_Float16)v;                       // v_cvt_f16_f32, RNE
    return __builtin_bit_cast(u16, h);
}
__device__ __forceinline__ float h2f(u16 u) {
    return (float)__builtin_bit_cast(_Float16, u);
}
__device__ __forceinline__ u16 split_hi(float v) { return f2h(v); }
__device__ __forceinline__ u16 split_lo(float v, u16 hi) {
    return f2h((v - h2f(hi)) * LOSCL);              // v-hi exact in fp32; *2^12 exact
}

// GELU via Abramowitz-Stegun 7.1.26 erf (max abs err 1.5e-7 — passed r14 at
// absmax 0.0078; tanh-GELU's 1e-3 failed r2).
__device__ __forceinline__ float gelu_fast(float x) {
    float ax = fabsf(x) * 0.70710678118654752f;     // |x|/sqrt(2)
    float t  = __builtin_amdgcn_rcpf(fmaf(0.3275911f, ax, 1.0f));
    float p  = fmaf(t, 1.061405429f, -1.453152027f);
    p = fmaf(t, p, 1.421413741f);
    p = fmaf(t, p, -0.284496736f);
    p = fmaf(t, p, 0.254829592f);
    p = p * t;
    float e  = __expf(-ax * ax);
    float er = fmaf(-p, e, 1.0f);
    er = copysignf(er, x);
    return 0.5f * x * (1.0f + er);
}

// MFMA 16x16x32 via builtin (r15: 32x32 regressed — AGPR accum round-trips,
// too few independent chains; 16x16 gives 12 chains of ILP per pass).
__device__ __forceinline__ void mfma16(f32x4& d, s16x8 a, s16x8 b) {
    d = __builtin_amdgcn_mfma_f32_16x16x32_f16(
            __builtin_bit_cast(h16x8, a), __builtin_bit_cast(h16x8, b), d, 0, 0, 0);
}
__device__ __forceinline__ s16x8 ldf(const u16* p) {
    return *reinterpret_cast<const s16x8*>(p);
}

// LDS chunk swizzle (r12/r13-validated layout; all sites agree).
__device__ __forceinline__ int swz(int row) {
    return (row & 7) ^ ((row & 8) >> 2);
}

// ---------------- weight prepack (identical to r11-r14) ----------------
// frag layout: base + ((nt*4 + kc)*2 + term)*512 + lane*8 + i   (u16 units)
// element: B[k = kc*32 + (lane>>4)*8 + i][n = nt*16 + (lane&15)]
// sigma column-deinterleaved: WG0 = sig_w[:,0::2], WG1 = sig_w[:,1::2]
__global__ void prepack(const float* __restrict__ enc_w, const float* __restrict__ mu_w1,
                        const float* __restrict__ mu_w2, const float* __restrict__ sig_w,
                        const float* __restrict__ dec_w, u16* __restrict__ wpk)
{
    int u = blockIdx.x * 256 + threadIdx.x;
    if (u >= WPK_TOT) return;
    int mat  = u >> 15;
    int r    = u & 32767;
    int i    = r & 7;
    int lane = (r >> 3) & 63;
    int term = (r >> 9) & 1;
    int kc   = (r >> 10) & 3;
    int nt   = (r >> 12) & 7;
    int k = kc * 32 + (lane >> 4) * 8 + i;
    int n = nt * 16 + (lane & 15);
    float v;
    switch (mat) {
        case 0:  v = enc_w[k * 128 + n];         break;
        case 1:  v = mu_w1[k * 128 + n];         break;
        case 2:  v = mu_w2[k * 128 + n];         break;
        case 3:  v = sig_w[k * 256 + 2 * n];     break;
        case 4:  v = sig_w[k * 256 + 2 * n + 1]; break;
        default: v = dec_w[k * 128 + n];         break;
    }
    u16 hi = split_hi(v);
    wpk[u] = term ? split_lo(v, hi) : hi;
}

// ---------------- main fused SDE kernel ----------------
// r16 reshape: 4 waves x 32 cols (2 nt) x BR=32 rows. A-panel read by 4 waves
// instead of 8 -> LDS reads/row 12 -> 8 (r14 post-mortem: LDS pipe = 75% of
// runtime). p2 nt-split caps accumulators at 32 f32 (B volume unchanged —
// B is per-nt anyway). LDS 33 KB -> 4 blocks/CU; grid 1024 = exact residency.
// Established invariants: no resident weights (L2 B-frags), asm "+s"
// LICM-blocker, MFMA builtin, fp16 hi/lo split state in LDS, zr in regs.
__global__ __launch_bounds__(NT) void sde_mfma(
    const float* __restrict__ y, const float* __restrict__ noise,
    const float* __restrict__ enc_b, const float* __restrict__ mu_b1,
    const float* __restrict__ mu_b2, const float* __restrict__ sig_b,
    const float* __restrict__ dec_b, const u16* __restrict__ wpk,
    float* __restrict__ out, int Btot)
{
    __shared__ __align__(16) u16 zbh[4096];
    __shared__ __align__(16) u16 zbl[4096];
    __shared__ __align__(16) u16 hbh[4096];
    __shared__ __align__(16) u16 hbl[4096];
    __shared__ float nsb[2][64];

    const int tid  = threadIdx.x;
    const int lane = tid & 63, wid = tid >> 6;      // wid 0..3
    const int ln   = lane & 15, lg = lane >> 4;
    const size_t brow = (size_t)blockIdx.x * BR;

    const int n0 = wid * 32 + ln, n1 = n0 + 16;     // this thread's two cols
    const float b10 = mu_b1[n0],  b11 = mu_b1[n1];
    const float b20 = mu_b2[n0],  b21 = mu_b2[n1];
    const float bg00 = sig_b[2 * n0],     bg01 = sig_b[2 * n1];
    const float bg10 = sig_b[2 * n0 + 1], bg11 = sig_b[2 * n1 + 1];
    const int swzl = swz(ln);                       // A-read chunk swizzle

    // ---- stage y into zb (fp16 hi/lo, swizzled) ----
    #pragma unroll
    for (int c = 0; c < 4; c++) {
        int q = c * NT + tid;                 // 0..1023
        int row = q >> 5, k4 = (q & 31) << 2;
        const float4 v = *reinterpret_cast<const float4*>(y + (brow + row) * 128 + k4);
        int idx = row * 128 + (((k4 >> 3) ^ swz(row)) << 3) + (k4 & 7);
        float vv[4] = {v.x, v.y, v.z, v.w};
        us4 hv, lv;
        #pragma unroll
        for (int e = 0; e < 4; e++) {
            u16 h = split_hi(vv[e]);
            u16 l = split_lo(vv[e], h);
            hv[e] = h; lv[e] = l;
        }
        *reinterpret_cast<us4*>(zbh + idx) = hv;
        *reinterpret_cast<us4*>(zbl + idx) = lv;
    }
    __syncthreads();

    float zr[2][2][4];   // z state [j][mt][r], fp32, carried across all 200 steps

    // ---- encoder: z0 = gelu(y @ enc_w + enc_b) ----
    {
        const float be0 = enc_b[n0], be1 = enc_b[n1];
        f32x4 a0[2][2], a1[2][2];
        #pragma unroll
        for (int mt = 0; mt < 2; mt++) {
            a0[0][mt] = f32x4{be0, be0, be0, be0}; a1[0][mt] = f32x4{0, 0, 0, 0};
            a0[1][mt] = f32x4{be1, be1, be1, be1}; a1[1][mt] = f32x4{0, 0, 0, 0};
        }
        #pragma unroll
        for (int kc = 0; kc < 4; kc++) {
            s16x8 ah[2], al[2];
            #pragma unroll
            for (int mt = 0; mt < 2; mt++) {
                int idx = (mt * 16 + ln) * 128 + ((((kc << 2) | lg) ^ swzl) << 3);
                ah[mt] = ldf(zbh + idx);
                al[mt] = ldf(zbl + idx);
            }
            #pragma unroll
            for (int j = 0; j < 2; j++) {
                int nt = wid * 2 + j;
                int fo = (((nt << 2) | kc) << 10) + (lane << 3);
                s16x8 bh = ldf(wpk + ENC_OFF + fo);
                s16x8 bl = ldf(wpk + ENC_OFF + fo + 512);
                #pragma unroll
                for (int mt = 0; mt < 2; mt++) {
                    mfma16(a0[j][mt], ah[mt], bh);
                    mfma16(a1[j][mt], al[mt], bh);
                    mfma16(a1[j][mt], ah[mt], bl);
                }
            }
        }
        #pragma unroll
        for (int j = 0; j < 2; j++)
            #pragma unroll
            for (int mt = 0; mt < 2; mt++)
                #pragma unroll
                for (int r = 0; r < 4; r++)
                    zr[j][mt][r] = gelu_fast(fmaf(a1[j][mt][r], LOINV, a0[j][mt][r]));
    }
    __syncthreads();   // all y-tile reads done

    // write z0 into zb; stage noise for t=0
    #pragma unroll
    for (int j = 0; j < 2; j++)
        #pragma unroll
        for (int mt = 0; mt < 2; mt++)
            #pragma unroll
            for (int r = 0; r < 4; r++) {
                int m = 16 * mt + 4 * lg + r, n = j ? n1 : n0;
                int idx = m * 128 + (((n >> 3) ^ swz(m)) << 3) + (n & 7);
                u16 h = split_hi(zr[j][mt][r]);
                zbh[idx] = h;
                zbl[idx] = split_lo(zr[j][mt][r], h);
            }
    if (tid < 64) nsb[0][tid] = noise[brow * 2 + tid];
    __syncthreads();

    // loop-opaque weight pointer: defeats LICM hoisting weight loads into
    // loop-carried registers (the scratch-spill source in r5-r10).
    const u16* wq = wpk;

    // ---- 200 Euler-Maruyama steps, 2 barriers each ----
    for (int t = 0; t < NSTEPS; t++) {
        asm volatile("" : "+s"(wq));
        {   // prefetch next step's noise into the other buffer
            int tn = (t + 1 < NSTEPS) ? (t + 1) : t;
            if (tid < 64) nsb[(t + 1) & 1][tid] = noise[((size_t)tn * Btot + brow) * 2 + tid];
        }
        // pass 1 — G1: h = gelu(z @ W1 + b1) -> hb  (W1 from L2)
        {
            f32x4 a0[2][2], a1[2][2];
            #pragma unroll
            for (int mt = 0; mt < 2; mt++) {
                a0[0][mt] = f32x4{b10, b10, b10, b10}; a1[0][mt] = f32x4{0, 0, 0, 0};
                a0[1][mt] = f32x4{b11, b11, b11, b11}; a1[1][mt] = f32x4{0, 0, 0, 0};
            }
            #pragma unroll
            for (int kc = 0; kc < 4; kc++) {
                s16x8 ah[2], al[2];
                #pragma unroll
                for (int mt = 0; mt < 2; mt++) {
                    int idx = (mt * 16 + ln) * 128 + ((((kc << 2) | lg) ^ swzl) << 3);
                    ah[mt] = ldf(zbh + idx);
                    al[mt] = ldf(zbl + idx);
                }
                #pragma unroll
                for (int j = 0; j < 2; j++) {
                    int nt = wid * 2 + j;
                    int fo = (((nt << 2) | kc) << 10) + (lane << 3);
                    s16x8 bh = ldf(wq + W1_OFF + fo);
                    s16x8 bl = ldf(wq + W1_OFF + fo + 512);
                    #pragma unroll
                    for (int mt = 0; mt < 2; mt++) {
                        mfma16(a0[j][mt], ah[mt], bh);
                        mfma16(a1[j][mt], al[mt], bh);
                        mfma16(a1[j][mt], ah[mt], bl);
                    }
                }
            }
            #pragma unroll
            for (int j = 0; j < 2; j++)
                #pragma unroll
                for (int mt = 0; mt < 2; mt++)
                    #pragma unroll
                    for (int r = 0; r < 4; r++) {
                        float hv = gelu_fast(fmaf(a1[j][mt][r], LOINV, a0[j][mt][r]));
                        int m = 16 * mt + 4 * lg + r, n = j ? n1 : n0;
                        int idx = m * 128 + (((n >> 3) ^ swz(m)) << 3) + (n & 7);
                        u16 h = split_hi(hv);
                        hbh[idx] = h;
                        hbl[idx] = split_lo(hv, h);
                    }
        }
        // pass 2 — sigma, nt-split (j sequential): zr[j] += g0*dw0 + g1*dw1.
        // Accum capped at 32 f32/j; A re-read per j is cheaper than B-doubling
        // (r12 lesson) and B here is per-nt anyway (no extra B volume).
        const float* np = nsb[t & 1];
        #pragma unroll 1
        for (int j = 0; j < 2; j++) {
            const float bgA = j ? bg01 : bg00;
            const float bgB = j ? bg11 : bg10;
            f32x4 q0h[2], q0l[2], q1h[2], q1l[2];
            #pragma unroll
            for (int mt = 0; mt < 2; mt++) {
                q0h[mt] = f32x4{bgA, bgA, bgA, bgA}; q0l[mt] = f32x4{0, 0, 0, 0};
                q1h[mt] = f32x4{bgB, bgB, bgB, bgB}; q1l[mt] = f32x4{0, 0, 0, 0};
            }
            const int nt = wid * 2 + j;
            #pragma unroll 2
            for (int kc = 0; kc < 4; kc++) {
                s16x8 ah[2], al[2];
                #pragma unroll
                for (int mt = 0; mt < 2; mt++) {
                    int idx = (mt * 16 + ln) * 128 + ((((kc << 2) | lg) ^ swzl) << 3);
                    ah[mt] = ldf(zbh + idx);
                    al[mt] = ldf(zbl + idx);
                }
                int fo = (((nt << 2) | kc) << 10) + (lane << 3);
                s16x8 b0h = ldf(wq + WG0_OFF + fo);
                s16x8 b0l = ldf(wq + WG0_OFF + fo + 512);
                s16x8 b1h = ldf(wq + WG1_OFF + fo);
                s16x8 b1l = ldf(wq + WG1_OFF + fo + 512);
                #pragma unroll
                for (int mt = 0; mt < 2; mt++) {
                    mfma16(q0h[mt], ah[mt], b0h);
                    mfma16(q0l[mt], al[mt], b0h);
                    mfma16(q0l[mt], ah[mt], b0l);
                    mfma16(q1h[mt], ah[mt], b1h);
                    mfma16(q1l[mt], al[mt], b1h);
                    mfma16(q1l[mt], ah[mt], b1l);
                }
            }
            #pragma unroll
            for (int mt = 0; mt < 2; mt++)
                #pragma unroll
                for (int r = 0; r < 4; r++) {
                    int m = 16 * mt + 4 * lg + r;
                    float dw0 = np[2 * m] * SQDT_F;
                    float dw1 = np[2 * m + 1] * SQDT_F;
                    float gv0 = fmaf(q0l[mt][r], LOINV, q0h[mt][r]);
                    float gv1 = fmaf(q1l[mt][r], LOINV, q1h[mt][r]);
                    zr[j][mt][r] = fmaf(gv0, dw0, fmaf(gv1, dw1, zr[j][mt][r]));
                }
        }
        __syncthreads();   // bar1: all zb reads done; hb visible

        // pass 3 — G2: drift = h @ W2 + b2; zr += drift*dt; rewrite zb
        {
            f32x4 a0[2][2], a1[2][2];
            #pragma unroll
            for (int mt = 0; mt < 2; mt++) {
                a0[0][mt] = f32x4{b20, b20, b20, b20}; a1[0][mt] = f32x4{0, 0, 0, 0};
                a0[1][mt] = f32x4{b21, b21, b21, b21}; a1[1][mt] = f32x4{0, 0, 0, 0};
            }
            #pragma unroll
            for (int kc = 0; kc < 4; kc++) {
                s16x8 ah[2], al[2];
                #pragma unroll
                for (int mt = 0; mt < 2; mt++) {
                    int idx = (mt * 16 + ln) * 128 + ((((kc << 2) | lg) ^ swzl) << 3);
                    ah[mt] = ldf(hbh + idx);
                    al[mt] = ldf(hbl + idx);
                }
                #pragma unroll
                for (int j = 0; j < 2; j++) {
                    int nt = wid * 2 + j;
                    int fo = (((nt << 2) | kc) << 10) + (lane << 3);
                    s16x8 bh = ldf(wq + W2_OFF + fo);
                    s16x8 bl = ldf(wq + W2_OFF + fo + 512);
                    #pragma unroll
                    for (int mt = 0; mt < 2; mt++) {
                        mfma16(a0[j][mt], ah[mt], bh);
                        mfma16(a1[j][mt], al[mt], bh);
                        mfma16(a1[j][mt], ah[mt], bl);
                    }
                }
            }
            #pragma unroll
            for (int j = 0; j < 2; j++)
                #pragma unroll
                for (int mt = 0; mt < 2; mt++)
                    #pragma unroll
                    for (int r = 0; r < 4; r++) {
                        float drift = fmaf(a1[j][mt][r], LOINV, a0[j][mt][r]);
                        float v = fmaf(drift, DT_F, zr[j][mt][r]);
                        zr[j][mt][r] = v;
                        int m = 16 * mt + 4 * lg + r, n = j ? n1 : n0;
                        int idx = m * 128 + (((n >> 3) ^ swz(m)) << 3) + (n & 7);
                        u16 h = split_hi(v);
                        zbh[idx] = h;
                        zbl[idx] = split_lo(v, h);
                    }
        }
        __syncthreads();   // bar2: new zb visible
    }

    // ---- decoder: out = z @ dec_w + dec_b ----
    {
        const float bd0 = dec_b[n0], bd1 = dec_b[n1];
        f32x4 a0[2][2], a1[2][2];
        #pragma unroll
        for (int mt = 0; mt < 2; mt++) {
            a0[0][mt] = f32x4{bd0, bd0, bd0, bd0}; a1[0][mt] = f32x4{0, 0, 0, 0};
            a0[1][mt] = f32x4{bd1, bd1, bd1, bd1}; a1[1][mt] = f32x4{0, 0, 0, 0};
        }
        #pragma unroll
        for (int kc = 0; kc < 4; kc++) {
            s16x8 ah[2], al[2];
            #pragma unroll
            for (int mt = 0; mt < 2; mt++) {
                int idx = (mt * 16 + ln) * 128 + ((((kc << 2) | lg) ^ swzl) << 3);
                ah[mt] = ldf(zbh + idx);
                al[mt] = ldf(zbl + idx);
            }
            #pragma unroll
            for (int j = 0; j < 2; j++) {
                int nt = wid * 2 + j;
                int fo = (((nt << 2) | kc) << 10) + (lane << 3);
                s16x8 bh = ldf(wpk + DEC_OFF + fo);
                s16x8 bl = ldf(wpk + DEC_OFF + fo + 512);
                #pragma unroll
                for (int mt = 0; mt < 2; mt++) {
                    mfma16(a0[j][mt], ah[mt], bh);
                    mfma16(a1[j][mt], al[mt], bh);
                    mfma16(a1[j][mt], ah[mt], bl);
                }
            }
        }
        #pragma unroll
        for (int j = 0; j < 2; j++)
            #pragma unroll
            for (int mt = 0; mt < 2; mt++)
                #pragma unroll
                for (int r = 0; r < 4; r++) {
                    int m = 16 * mt + 4 * lg + r, n = j ? n1 : n0;
                    out[(brow + m) * 128 + n] = fmaf(a1[j][mt][r], LOINV, a0[j][mt][r]);
                }
    }
}

extern "C" void kernel_launch(void* const* d_in, const int* in_sizes, int n_in,
                              void* d_out, int out_size, void* d_ws, size_t ws_size,
                              hipStream_t stream) {
    const float* y     = (const float*)d_in[0];
    const float* noise = (const float*)d_in[1];
    const float* enc_w = (const float*)d_in[2];
    const float* enc_b = (const float*)d_in[3];
    const float* mu_w1 = (const float*)d_in[4];
    const float* mu_b1 = (const float*)d_in[5];
    const float* mu_w2 = (const float*)d_in[6];
    const float* mu_b2 = (const float*)d_in[7];
    const float* sig_w = (const float*)d_in[8];
    const float* sig_b = (const float*)d_in[9];
    const float* dec_w = (const float*)d_in[10];
    const float* dec_b = (const float*)d_in[11];
    float* out = (float*)d_out;
    u16* wpk = (u16*)d_ws;

    const int Btot = in_sizes[0] / 128;     // 32768
    prepack<<<(WPK_TOT + 255) / 256, 256, 0, stream>>>(enc_w, mu_w1, mu_w2, sig_w, dec_w, wpk);
    sde_mfma<<<Btot / BR, NT, 0, stream>>>(y, noise, enc_b, mu_b1, mu_b2, sig_b, dec_b,
                                           wpk, out, Btot);
}

// Round 17
// 5220.278 us; speedup vs baseline: 1.0416x; 1.0416x over previous
//
#include <hip/hip_runtime.h>
#include <math.h>

#define NSTEPS 200
#define NT     256          // 4 waves; wave w owns j/n-quarter [32w,32w+32) and kc-block w
#define BR     16           // 16 batch rows per block (m = lane&15)
#define SQDT_F 0.07071067811865475f
#define DT_F   0.005f
#define LOSCL  4096.0f            // 2^12
#define LOINV  2.44140625e-4f     // 2^-12

typedef float  f32x4 __attribute__((ext_vector_type(4)));
typedef short  s16x8 __attribute__((ext_vector_type(8)));
typedef _Float16 h16x8 __attribute__((ext_vector_type(8)));
typedef unsigned short u16;

// prepacked weight offsets in u16 units (each 128x128 matrix = 32768 u16, A^T-frags)
#define ENC_OFF 0
#define W1_OFF  32768
#define W2_OFF  65536
#define WG0_OFF 98304
#define WG1_OFF 131072
#define DEC_OFF 163840
#define WPK_TOT 196608

// ---- fp16 scaled two-term split: x ~= hi + lo*2^-12, |err| <= ~2^-23 |x| ----
__device__ __forceinline__ u16 f2h(float v) {
    _Float16 h = (_Float16)v;                       // v_cvt_f16_f32, RNE
    return __builtin_bit_cast(u16, h);
}
__device__ __forceinline__ float h2f(u16 u) {
    return (float)__builtin_bit_cast(_Float16, u);
}
__device__ __forceinline__ u16 split_hi(float v) { return f2h(v); }
__device__ __forceinline__ u16 split_lo(float v, u16 hi) {
    return f2h((v - h2f(hi)) * LOSCL);              // v-hi exact in fp32; *2^12 exact
}

// GELU via Abramowitz-Stegun 7.1.26 erf (max abs err 1.5e-7 — passed r14 at
// absmax 0.0078; tanh-GELU's 1e-3 failed r2).
__device__ __forceinline__ float gelu_fast(float x) {
    float ax = fabsf(x) * 0.70710678118654752f;     // |x|/sqrt(2)
    float t  = __builtin_amdgcn_rcpf(fmaf(0.3275911f, ax, 1.0f));
    float p  = fmaf(t, 1.061405429f, -1.453152027f);
    p = fmaf(t, p, 1.421413741f);
    p = fmaf(t, p, -0.284496736f);
    p = fmaf(t, p, 0.254829592f);
    p = p * t;
    float e  = __expf(-ax * ax);
    float er = fmaf(-p, e, 1.0f);
    er = copysignf(er, x);
    return 0.5f * x * (1.0f + er);
}

// MFMA builtin (compiler models hazards; r6/r7 inline-asm MFMA NaN'd).
// d = A@B + d; A = weight^T frags, B = state^T frags.
__device__ __forceinline__ void mfma16(f32x4& d, s16x8 a, s16x8 b) {
    d = __builtin_amdgcn_mfma_f32_16x16x32_f16(
            __builtin_bit_cast(h16x8, a), __builtin_bit_cast(h16x8, b), d, 0, 0, 0);
}
__device__ __forceinline__ s16x8 ldf(const u16* p) {
    return *reinterpret_cast<const s16x8*>(p);
}

// ---------------- weight prepack: fp32 -> fp16 hi / scaled-lo A^T fragments ----
// Swapped-GEMM k-slot map (MUST match the C-layout->B-frag chaining):
//   slot i of lane l holds k = kc*32 + 16*(i>>2) + 4*(l>>4) + (i&3)
// A-row (output j/n dim) = tile*16 + (l&15). Contraction is k-permutation-
// invariant because A (here) and B (built from C-layout in-kernel) use the
// SAME map. frag addr: base + ((tile*4 + kc)*2 + term)*512 + lane*8 + i.
// sigma column-deinterleaved: WG0 = sig_w[:,0::2], WG1 = sig_w[:,1::2].
__global__ void prepack(const float* __restrict__ enc_w, const float* __restrict__ mu_w1,
                        const float* __restrict__ mu_w2, const float* __restrict__ sig_w,
                        const float* __restrict__ dec_w, u16* __restrict__ wpk)
{
    int u = blockIdx.x * 256 + threadIdx.x;
    if (u >= WPK_TOT) return;
    int mat  = u >> 15;
    int r    = u & 32767;
    int i    = r & 7;
    int lane = (r >> 3) & 63;
    int term = (r >> 9) & 1;
    int kc   = (r >> 10) & 3;
    int nt   = (r >> 12) & 7;
    int k = kc * 32 + 16 * (i >> 2) + 4 * (lane >> 4) + (i & 3);   // swapped k-map
    int n = nt * 16 + (lane & 15);
    float v;
    switch (mat) {
        case 0:  v = enc_w[k * 128 + n];         break;
        case 1:  v = mu_w1[k * 128 + n];         break;
        case 2:  v = mu_w2[k * 128 + n];         break;
        case 3:  v = sig_w[k * 256 + 2 * n];     break;
        case 4:  v = sig_w[k * 256 + 2 * n + 1]; break;
        default: v = dec_w[k * 128 + n];         break;
    }
    u16 hi = split_hi(v);
    wpk[u] = term ? split_lo(v, hi) : hi;
}

// ---------------- main fused SDE kernel (swapped-operand, register-chained) ----
// All GEMMs computed transposed: x^T-tiles land in C-layout
// (thread holds x^T[16*tile + 4*lg + r][m=ln]) which IS the next GEMM's
// B-frag under the shared k-map -> z and h never round-trip row-major LDS.
// Per step LDS: 4 b128 writes + 16 b128 reads per wave (vs r14's 96r+64w).
// Weights stream from L2 (loop-opaque wq blocks LICM -> no spill, r11).
// Biases read from LDS via volatile (blocks LICM reg pinning).
__global__ __launch_bounds__(NT) void sde_mfma(
    const float* __restrict__ y, const float* __restrict__ noise,
    const float* __restrict__ enc_b, const float* __restrict__ mu_b1,
    const float* __restrict__ mu_b2, const float* __restrict__ sig_b,
    const float* __restrict__ dec_b, const u16* __restrict__ wpk,
    float* __restrict__ out, int Btot)
{
    __shared__ __align__(16) u16 zx[2][4][2][512];   // [buf][owner kc][term][lane*8]
    __shared__ __align__(16) u16 hx[4][2][512];      // h^T frag exchange
    __shared__ float bb[4][128];                     // b1, b2, bg0, bg1
    __shared__ float nsb[2][32];

    const int tid  = threadIdx.x;
    const int lane = tid & 63, wid = tid >> 6;       // wid 0..3
    const int ln   = lane & 15, lg = lane >> 4;
    const size_t brow = (size_t)blockIdx.x * BR;

    if (tid < 128) {
        bb[0][tid] = mu_b1[tid];
        bb[1][tid] = mu_b2[tid];
        bb[2][tid] = sig_b[2 * tid];
        bb[3][tid] = sig_b[2 * tid + 1];
    }
    if (tid < 32) nsb[0][tid] = noise[(brow + (tid >> 1)) * 2 + (tid & 1)];
    volatile const float (*bbv)[128] = (volatile const float (*)[128])bb;

    float zm[2][4];   // z[m=ln][c = 32*wid + 16*s + 4*lg + r], fp32 master

    // ---- encoder: z0^T = gelu(enc^T @ y^T) for own c-quarter ----
    {
        s16x8 yfh[4], yfl[4];
        #pragma unroll
        for (int kc = 0; kc < 4; kc++) {
            float vv[8];
            #pragma unroll
            for (int s = 0; s < 2; s++) {
                const float4 v = *reinterpret_cast<const float4*>(
                    y + (brow + ln) * 128 + kc * 32 + 16 * s + 4 * lg);
                vv[4*s+0] = v.x; vv[4*s+1] = v.y; vv[4*s+2] = v.z; vv[4*s+3] = v.w;
            }
            s16x8 th, tl;
            #pragma unroll
            for (int e = 0; e < 8; e++) {
                u16 hh = split_hi(vv[e]);
                th[e] = (short)hh;
                tl[e] = (short)split_lo(vv[e], hh);
            }
            yfh[kc] = th; yfl[kc] = tl;
        }
        #pragma unroll
        for (int s = 0; s < 2; s++) {
            const int jt = 2 * wid + s;
            f32x4 a0, a1;
            #pragma unroll
            for (int r = 0; r < 4; r++) { a0[r] = enc_b[16 * jt + 4 * lg + r]; a1[r] = 0.0f; }
            #pragma unroll
            for (int kc = 0; kc < 4; kc++) {
                const u16* ap = wpk + ENC_OFF + ((jt * 4 + kc) * 2) * 512 + lane * 8;
                s16x8 wh = ldf(ap), wl = ldf(ap + 512);
                mfma16(a0, wh, yfh[kc]);
                mfma16(a1, wl, yfh[kc]);
                mfma16(a1, wh, yfl[kc]);
            }
            #pragma unroll
            for (int r = 0; r < 4; r++)
                zm[s][r] = gelu_fast(fmaf(a1[r], LOINV, a0[r]));
        }
    }
    __syncthreads();   // bb/nsb staged

    // loop-opaque weight pointer: defeats LICM of weight loads (r5-r10 spill fix)
    const u16* wq = wpk;

    for (int t = 0; t < NSTEPS; t++) {
        asm volatile("" : "+s"(wq));
        {   // prefetch next step's noise
            int tn = (t + 1 < NSTEPS) ? (t + 1) : t;
            if (tid < 32)
                nsb[(t + 1) & 1][tid] = noise[((size_t)tn * Btot + brow + (tid >> 1)) * 2 + (tid & 1)];
        }
        // split own z-quarter -> frags, publish (slot i = 4s+r by construction)
        {
            s16x8 th, tl;
            #pragma unroll
            for (int e = 0; e < 8; e++) {
                float v = zm[e >> 2][e & 3];
                u16 hh = split_hi(v);
                th[e] = (short)hh;
                tl[e] = (short)split_lo(v, hh);
            }
            *reinterpret_cast<s16x8*>(&zx[t & 1][wid][0][lane * 8]) = th;
            *reinterpret_cast<s16x8*>(&zx[t & 1][wid][1][lane * 8]) = tl;
        }
        __syncthreads();   // bar_A: z^T frags visible

        s16x8 zfh[4], zfl[4];
        #pragma unroll
        for (int kc = 0; kc < 4; kc++) {
            zfh[kc] = ldf(&zx[t & 1][kc][0][lane * 8]);
            zfl[kc] = ldf(&zx[t & 1][kc][1][lane * 8]);
        }

        // G1 swapped: h^T[j-quarter][m] = W1^T @ z^T
        float hvv[2][4];
        #pragma unroll
        for (int s = 0; s < 2; s++) {
            const int jt = 2 * wid + s;
            f32x4 a0, a1;
            #pragma unroll
            for (int r = 0; r < 4; r++) { a0[r] = bbv[0][16 * jt + 4 * lg + r]; a1[r] = 0.0f; }
            #pragma unroll
            for (int kc = 0; kc < 4; kc++) {
                const u16* ap = wq + W1_OFF + ((jt * 4 + kc) * 2) * 512 + lane * 8;
                s16x8 wh = ldf(ap), wl = ldf(ap + 512);
                mfma16(a0, wh, zfh[kc]);
                mfma16(a1, wl, zfh[kc]);
                mfma16(a1, wh, zfl[kc]);
            }
            #pragma unroll
            for (int r = 0; r < 4; r++)
                hvv[s][r] = gelu_fast(fmaf(a1[r], LOINV, a0[r]));
        }
        // publish own h^T frags
        {
            s16x8 th, tl;
            #pragma unroll
            for (int e = 0; e < 8; e++) {
                float v = hvv[e >> 2][e & 3];
                u16 hh = split_hi(v);
                th[e] = (short)hh;
                tl[e] = (short)split_lo(v, hh);
            }
            *reinterpret_cast<s16x8*>(&hx[wid][0][lane * 8]) = th;
            *reinterpret_cast<s16x8*>(&hx[wid][1][lane * 8]) = tl;
        }

        // G3 swapped sigma: g^T[n-quarter][m]; update own z-quarter
        {
            const float dw0 = nsb[t & 1][2 * ln] * SQDT_F;
            const float dw1 = nsb[t & 1][2 * ln + 1] * SQDT_F;
            #pragma unroll
            for (int s = 0; s < 2; s++) {
                const int nt = 2 * wid + s;
                f32x4 q0h, q0l, q1h, q1l;
                #pragma unroll
                for (int r = 0; r < 4; r++) {
                    q0h[r] = bbv[2][16 * nt + 4 * lg + r]; q0l[r] = 0.0f;
                    q1h[r] = bbv[3][16 * nt + 4 * lg + r]; q1l[r] = 0.0f;
                }
                #pragma unroll
                for (int kc = 0; kc < 4; kc++) {
                    const u16* p0 = wq + WG0_OFF + ((nt * 4 + kc) * 2) * 512 + lane * 8;
                    const u16* p1 = wq + WG1_OFF + ((nt * 4 + kc) * 2) * 512 + lane * 8;
                    s16x8 w0h = ldf(p0), w0l = ldf(p0 + 512);
                    s16x8 w1h = ldf(p1), w1l = ldf(p1 + 512);
                    mfma16(q0h, w0h, zfh[kc]);
                    mfma16(q0l, w0l, zfh[kc]);
                    mfma16(q0l, w0h, zfl[kc]);
                    mfma16(q1h, w1h, zfh[kc]);
                    mfma16(q1l, w1l, zfh[kc]);
                    mfma16(q1l, w1h, zfl[kc]);
                }
                #pragma unroll
                for (int r = 0; r < 4; r++) {
                    float gv0 = fmaf(q0l[r], LOINV, q0h[r]);
                    float gv1 = fmaf(q1l[r], LOINV, q1h[r]);
                    zm[s][r] = fmaf(gv0, dw0, fmaf(gv1, dw1, zm[s][r]));
                }
            }
        }
        __syncthreads();   // bar_B: h^T frags visible; zx[t&1] reads complete

        // G2 swapped: drift^T[n-quarter][m] = W2^T @ h^T; z += drift*dt
        {
            s16x8 hfh[4], hfl[4];
            #pragma unroll
            for (int kc = 0; kc < 4; kc++) {
                hfh[kc] = ldf(&hx[kc][0][lane * 8]);
                hfl[kc] = ldf(&hx[kc][1][lane * 8]);
            }
            #pragma unroll
            for (int s = 0; s < 2; s++) {
                const int nt = 2 * wid + s;
                f32x4 a0, a1;
                #pragma unroll
                for (int r = 0; r < 4; r++) { a0[r] = bbv[1][16 * nt + 4 * lg + r]; a1[r] = 0.0f; }
                #pragma unroll
                for (int kc = 0; kc < 4; kc++) {
                    const u16* ap = wq + W2_OFF + ((nt * 4 + kc) * 2) * 512 + lane * 8;
                    s16x8 wh = ldf(ap), wl = ldf(ap + 512);
                    mfma16(a0, wh, hfh[kc]);
                    mfma16(a1, wl, hfh[kc]);
                    mfma16(a1, wh, hfl[kc]);
                }
                #pragma unroll
                for (int r = 0; r < 4; r++)
                    zm[s][r] = fmaf(fmaf(a1[r], LOINV, a0[r]), DT_F, zm[s][r]);
            }
        }
    }

    // ---- decoder: out^T[n-quarter][m] = dec^T @ z^T (one final exchange) ----
    {
        s16x8 th, tl;
        #pragma unroll
        for (int e = 0; e < 8; e++) {
            float v = zm[e >> 2][e & 3];
            u16 hh = split_hi(v);
            th[e] = (short)hh;
            tl[e] = (short)split_lo(v, hh);
        }
        *reinterpret_cast<s16x8*>(&zx[0][wid][0][lane * 8]) = th;
        *reinterpret_cast<s16x8*>(&zx[0][wid][1][lane * 8]) = tl;
    }
    __syncthreads();
    {
        s16x8 zfh[4], zfl[4];
        #pragma unroll
        for (int kc = 0; kc < 4; kc++) {
            zfh[kc] = ldf(&zx[0][kc][0][lane * 8]);
            zfl[kc] = ldf(&zx[0][kc][1][lane * 8]);
        }
        #pragma unroll
        for (int s = 0; s < 2; s++) {
            const int nt = 2 * wid + s;
            f32x4 a0, a1;
            #pragma unroll
            for (int r = 0; r < 4; r++) { a0[r] = dec_b[16 * nt + 4 * lg + r]; a1[r] = 0.0f; }
            #pragma unroll
            for (int kc = 0; kc < 4; kc++) {
                const u16* ap = wpk + DEC_OFF + ((nt * 4 + kc) * 2) * 512 + lane * 8;
                s16x8 wh = ldf(ap), wl = ldf(ap + 512);
                mfma16(a0, wh, zfh[kc]);
                mfma16(a1, wl, zfh[kc]);
                mfma16(a1, wh, zfl[kc]);
            }
            #pragma unroll
            for (int r = 0; r < 4; r++)
                out[(brow + ln) * 128 + 16 * nt + 4 * lg + r] = fmaf(a1[r], LOINV, a0[r]);
        }
    }
}

extern "C" void kernel_launch(void* const* d_in, const int* in_sizes, int n_in,
                              void* d_out, int out_size, void* d_ws, size_t ws_size,
                              hipStream_t stream) {
    const float* y     = (const float*)d_in[0];
    const float* noise = (const float*)d_in[1];
    const float* enc_w = (const float*)d_in[2];
    const float* enc_b = (const float*)d_in[3];
    const float* mu_w1 = (const float*)d_in[4];
    const float* mu_b1 = (const float*)d_in[5];
    const float* mu_w2 = (const float*)d_in[6];
    const float* mu_b2 = (const float*)d_in[7];
    const float* sig_w = (const float*)d_in[8];
    const float* sig_b = (const float*)d_in[9];
    const float* dec_w = (const float*)d_in[10];
    const float* dec_b = (const float*)d_in[11];
    float* out = (float*)d_out;
    u16* wpk = (u16*)d_ws;

    const int Btot = in_sizes[0] / 128;     // 32768
    prepack<<<(WPK_TOT + 255) / 256, 256, 0, stream>>>(enc_w, mu_w1, mu_w2, sig_w, dec_w, wpk);
    sde_mfma<<<Btot / BR, NT, 0, stream>>>(y, noise, enc_b, mu_b1, mu_b2, sig_b, dec_b,
                                           wpk, out, Btot);
}